// Round 11
// baseline (150.973 us; speedup 1.0000x reference)
//
#include <hip/hip_runtime.h>

typedef __attribute__((ext_vector_type(8))) short          bf16x8;
typedef __attribute__((ext_vector_type(8))) unsigned short u16x8;
typedef __attribute__((ext_vector_type(4))) unsigned short u16x4;
typedef __attribute__((ext_vector_type(4))) float          f32x4;
typedef __attribute__((ext_vector_type(4))) unsigned int   u32x4;

union U8 { u16x8 u; bf16x8 b; u32x4 w; };
union U4 { u16x4 u; unsigned w[2]; };

__device__ __forceinline__ unsigned short f2bf(float f){
  unsigned u = __float_as_uint(f);
  return (unsigned short)((u + 0x7fffu + ((u >> 16) & 1u)) >> 16);
}
// pack two floats to bf16x2 (round-half-up): lo->low16, hi->high16. exact 0 preserved.
__device__ __forceinline__ unsigned pack_bf16(float lo, float hi){
  unsigned a = __float_as_uint(hi) + 0x8000u;
  unsigned b = __float_as_uint(lo) + 0x8000u;
  return __builtin_amdgcn_perm(a, b, 0x07060302u);
}
// max-pair -> packed bf16 (RNE) -> halfword mask (0xFFFF/0x0000 halves).
__device__ __forceinline__ unsigned maskpack(float e0, float e1, unsigned m){
  unsigned r;
  asm("v_cvt_pk_bf16_f32 %0, %1, %2" : "=v"(r) : "v"(e0), "v"(e1));
  return r & m;
}
// bits (off, off+1) of m -> halfword mask u32 {lo16 = bit off, hi16 = bit off+1}.
// Pure VALU (v_bfe_i32 x2 + v_perm); correctness-proven in R8. Used here
// because LDS is fully occupied by the 8-head exp tables (no room for a LUT).
__device__ __forceinline__ unsigned bit2half(unsigned m, unsigned off){
  unsigned lo = __builtin_amdgcn_sbfe((int)m, off, 1u);
  unsigned hi = __builtin_amdgcn_sbfe((int)m, off + 1u, 1u);
  return __builtin_amdgcn_perm(hi, lo, 0x05040100u);
}

#define NN  1024
#define FIN 256
#define NH  8
#define FO  64

// ---------------------------------------------------------------------------
// Stage 0: wfrag = w in MFMA-B-frag layout only. grid 64 x 256. (R10-exact.)
// ---------------------------------------------------------------------------
__global__ __launch_bounds__(256) void stage0(
    const float* __restrict__ w, unsigned short* __restrict__ wfrag)
{
  const int tid = blockIdx.x * 256 + threadIdx.x;
  const int lane = tid & 63, ss = (tid >> 6) & 3, kc = (tid >> 8) & 7, h = tid >> 11;
  const int o = 16 * ss + (lane & 15);
  const int f = kc * 32 + (lane >> 4) * 8;
  u16x8 r;
  #pragma unroll
  for (int j = 0; j < 8; j++) r[j] = f2bf(w[(h * FIN + f + j) * FO + o]);
  *(u16x8*)(wfrag + tid * 8) = r;
}

// ---------------------------------------------------------------------------
// Stage A: R10-exact. Flat grid 512, b = fid&7 (b-affine: batch b's hT panel,
// exp tables and Abits all land in XCD b's L2 -- the L2 attnBC reads; R10
// measured this placement at -6us). 512-thr blocks, 8 waves = 8 heads.
// ---------------------------------------------------------------------------
__global__ __launch_bounds__(512, 4) void stageA(
    const float* __restrict__ x, const float* __restrict__ e_at,
    const float* __restrict__ Np, const unsigned short* __restrict__ wfrag,
    const float* __restrict__ a_src, const float* __restrict__ a_dst,
    const int* __restrict__ A, unsigned long long* __restrict__ Abits,
    unsigned short* __restrict__ hT,
    float* __restrict__ Rt, float* __restrict__ expd, float* __restrict__ expd2)
{
  __shared__ unsigned short rex[16 * 264];   // 16 rows x 256 f, pad 264
  const int t = threadIdx.x;
  const int fid = blockIdx.x;                // 512 blocks
  const int b = fid & 7, tile = fid >> 3;    // tile in [0,64)
  const int n0 = tile * 16;

  {                                          // cooperative recx tile build
    const int row = t >> 5, f0 = (t & 31) * 8;
    const int nrow = n0 + row;
    const float* ep = e_at + (b * NN + nrow) * FIN + f0;
    const float* qp = Np + nrow * FIN + f0;
    const float* xp = x + b * FIN + f0;
    f32x4 e0 = *(const f32x4*)ep, e1 = *(const f32x4*)(ep + 4);
    f32x4 q0 = *(const f32x4*)qp, q1 = *(const f32x4*)(qp + 4);
    f32x4 x0 = *(const f32x4*)xp, x1 = *(const f32x4*)(xp + 4);
    u16x8 r;
    #pragma unroll
    for (int j = 0; j < 4; j++){
      r[j]     = f2bf(e0[j] * q0[j] * x0[j]);
      r[j + 4] = f2bf(e1[j] * q1[j] * x1[j]);
    }
    *(u16x8*)(rex + row * 264 + f0) = r;
  }
  __syncthreads();

  const int h = t >> 6, lane = t & 63, quad = lane >> 4, l15 = lane & 15;
  const unsigned short* wf = wfrag + h * 16384 + lane * 8;

  f32x4 acc[4] = {};
  #pragma unroll
  for (int kc = 0; kc < 8; kc++){
    U8 a0, bf[4];
    a0.u = *(const u16x8*)(rex + l15 * 264 + kc * 32 + quad * 8);
    #pragma unroll
    for (int ss = 0; ss < 4; ss++) bf[ss].u = *(const u16x8*)(wf + (kc * 4 + ss) * 512);
    #pragma unroll
    for (int ss = 0; ss < 4; ss++)
      acc[ss] = __builtin_amdgcn_mfma_f32_16x16x32_bf16(a0.b, bf[ss].b, acc[ss], 0, 0, 0);
  }

  // panel store: [b,h,mtile,o(64),m(32)], C/D row(n)=quad*4+i, col(o)=16ss+l15
  {
    const int mtile = tile >> 1, moff = (tile & 1) * 16;
    unsigned short* pan = hT + (size_t)(((b * NH + h) * 32 + mtile) * 64) * 32;
    #pragma unroll
    for (int ss = 0; ss < 4; ss++){
      U4 v;
      v.w[0] = pack_bf16(acc[ss][0], acc[ss][1]);
      v.w[1] = pack_bf16(acc[ss][2], acc[ss][3]);
      *(u16x4*)(pan + (16 * ss + l15) * 32 + moff + quad * 4) = v.u;
    }
  }

  // s/d reductions -> exp tables (R = exp(0.8 s): row factor exp(0.2 s) cancels
  // in softmax, so P' = max(R*Ed, Ed2) gives identical attention weights)
  float as4[4], ad4[4];
  #pragma unroll
  for (int ss = 0; ss < 4; ss++){
    as4[ss] = a_src[h * FO + 16 * ss + l15];
    ad4[ss] = a_dst[h * FO + 16 * ss + l15];
  }
  #pragma unroll
  for (int i = 0; i < 4; i++){
    float ps = 0.f, pd = 0.f;
    #pragma unroll
    for (int ss = 0; ss < 4; ss++){ ps += acc[ss][i] * as4[ss]; pd += acc[ss][i] * ad4[ss]; }
    #pragma unroll
    for (int off = 1; off < 16; off <<= 1){
      ps += __shfl_xor(ps, off);
      pd += __shfl_xor(pd, off);
    }
    if (l15 == 0){
      const int idx = (b * NH + h) * NN + n0 + quad * 4 + i;
      Rt[idx]    = __expf(0.8f * ps);
      expd[idx]  = __expf(pd);
      expd2[idx] = __expf(0.2f * pd);
    }
  }

  // tail: adjacency bit-pack, b-affine (batch b's rows packed on XCD b)
  {
    const int seg = b * 1048576 + tile * 16384;      // int base
    #pragma unroll 4
    for (int k = 0; k < 32; k++){
      const int i = seg + k * 512 + t;
      unsigned long long m = __ballot(A[i] > 0);
      if ((t & 63) == 0) Abits[i >> 6] = m;
    }
  }
}

// ---------------------------------------------------------------------------
// Stage BC (R11): fused masked-softmax aggregation + head mean -- stageC and
// the 34MB hpart round-trip are eliminated. 512 blocks x 512 thr; block =
// (b = fid&7, 16-row tile); 8 waves = 8 heads. Each wave owns its head's FULL
// 512-col range (32 iters, single row-group): complete denominators
// in-register (no m-merge), acc[4]+accl ~ 100 VGPR under the (512,4)=128
// budget (R3/R9 spill lesson). LDS = exactly 64KB: exp tables for all 8
// heads (reused post-loop as the head-merge buffer) -> 2 blocks/CU =
// 16 waves/CU (same occupancy as R10's attnB). Masks via VALU bit2half
// (R8-proven; LDS has no room for the LUT). Head merge: normalize
// in-register, park per-head in LDS, one barrier, 8-way sum + bias + mz,
// coalesced 2MB store to out. ZERO atomics, ZERO fences (R6 lesson).
// Pan traffic doubles vs R10 (536MB) but is XCD-local L2 after R10's
// b-affine stageA.
// ---------------------------------------------------------------------------
__global__ __launch_bounds__(512, 4) void attnBC(
    const unsigned* __restrict__ Aw,
    const unsigned short* __restrict__ hT,
    const float* __restrict__ Rt,
    const float* __restrict__ expd, const float* __restrict__ expd2,
    const float* __restrict__ bias, const float* __restrict__ mz,
    float* __restrict__ out)
{
  // phase 1: smem[0..8191] = Ed[8][1024], smem[8192..16383] = Ed2[8][1024]
  // phase 2: smem[0..8319] = buf[8][16][65] head-merge buffer
  __shared__ float smem[16384];              // 64 KB

  const int fid = blockIdx.x;
  const int b = fid & 7, rt = fid >> 3;      // rt in [0,64)
  const int n0 = rt * 16;

  const int t = threadIdx.x;                 // 512
  const int h = t >> 6, lane = t & 63, quad = lane >> 4, l15 = lane & 15;

  // exp-table preload: all 8 heads of batch b (contiguous, coalesced)
  #pragma unroll
  for (int k = 0; k < 4; k++){
    *(f32x4*)(smem + k * 2048 + t * 4) =
        *(const f32x4*)(expd + b * 8192 + k * 2048 + t * 4);
    *(f32x4*)(smem + 8192 + k * 2048 + t * 4) =
        *(const f32x4*)(expd2 + b * 8192 + k * 2048 + t * 4);
  }
  __syncthreads();

  const float Rv = Rt[(b * NH + h) * NN + n0 + l15];
  const unsigned short* pb = hT + (size_t)(b * NH + h) * 65536 + l15 * 32 + quad * 8;
  const float* edh = smem + h * 1024 + quad * 8;
  const float* e2h = smem + 8192 + h * 1024 + quad * 8;
  const unsigned* awp = Aw + (b * NN + n0) * 32;
  const unsigned qs = (unsigned)(quad * 8);

  // pipeline prologue: iter 0's pan frags + mask word
  U8 panc[4], pann[4];
  #pragma unroll
  for (int ss = 0; ss < 4; ss++)
    panc[ss].u = *(const u16x8*)(pb + ss * 512);
  unsigned mwc = awp[l15 * 32], mwn;

  U8 ones;                               // bf16 1.0 B-frag for row sums
  #pragma unroll
  for (int j = 0; j < 8; j++) ones.u[j] = 0x3F80;

  f32x4 acc[4] = {};
  f32x4 accl = {};

  #pragma unroll
  for (int c = 0; c < 32; c++){
    // prefetch iter c+1 first (L2 latency overlaps this whole iter)
    if (c + 1 < 32){
      #pragma unroll
      for (int ss = 0; ss < 4; ss++)
        pann[ss].u = *(const u16x8*)(pb + (size_t)(c + 1) * 2048 + ss * 512);
      mwn = awp[l15 * 32 + c + 1];
    }
    // expand bit mask in VALU
    const unsigned lax = bit2half(mwc, qs + 0u), lay = bit2half(mwc, qs + 2u);
    const unsigned lbx = bit2half(mwc, qs + 4u), lby = bit2half(mwc, qs + 6u);
    // shared column factors (broadcast LDS reads, conflict-free)
    const f32x4 d01 = *(const f32x4*)(edh + c * 32);
    const f32x4 d23 = *(const f32x4*)(edh + c * 32 + 4);
    const f32x4 g01 = *(const f32x4*)(e2h + c * 32);
    const f32x4 g23 = *(const f32x4*)(e2h + c * 32 + 4);
    const f32x4 p01 = Rv * d01, p23 = Rv * d23;
    U8 p;
    p.w[0] = maskpack(fmaxf(p01[0], g01[0]), fmaxf(p01[1], g01[1]), lax);
    p.w[1] = maskpack(fmaxf(p01[2], g01[2]), fmaxf(p01[3], g01[3]), lay);
    p.w[2] = maskpack(fmaxf(p23[0], g23[0]), fmaxf(p23[1], g23[1]), lbx);
    p.w[3] = maskpack(fmaxf(p23[2], g23[2]), fmaxf(p23[3], g23[3]), lby);
    #pragma unroll
    for (int ss = 0; ss < 4; ss++)
      acc[ss] = __builtin_amdgcn_mfma_f32_16x16x32_bf16(p.b, panc[ss].b, acc[ss], 0, 0, 0);
    accl = __builtin_amdgcn_mfma_f32_16x16x32_bf16(p.b, ones.b, accl, 0, 0, 0);
    // rotate (vanishes under full unroll via renaming)
    if (c + 1 < 32){
      #pragma unroll
      for (int ss = 0; ss < 4; ss++) panc[ss] = pann[ss];
      mwc = mwn;
    }
  }

  __syncthreads();                       // tables dead; smem becomes merge buffer

  // normalize in-register (accl[i] = complete row denominator, replicated
  // over l15) and park per-head: buf[h][16][65]
  float* buf = smem;
  #pragma unroll
  for (int i = 0; i < 4; i++){
    const float inv = 1.0f / accl[i];
    #pragma unroll
    for (int ss = 0; ss < 4; ss++)
      buf[h * 1040 + (quad * 4 + i) * 65 + ss * 16 + l15] = acc[ss][i] * inv;
  }
  __syncthreads();

  // head mean + bias + mz; coalesced store (1024 elems, 2 per thread)
  #pragma unroll
  for (int k = 0; k < 2; k++){
    const int e = k * 512 + t;
    const int row = e >> 6, col = e & 63;
    float s = 0.f;
    #pragma unroll
    for (int hh = 0; hh < NH; hh++) s += buf[hh * 1040 + row * 65 + col];
    out[(size_t)(b * NN + n0 + row) * FO + col] =
        (0.125f * s + bias[col]) * mz[b * NN + n0 + row];
  }
}

extern "C" void kernel_launch(void* const* d_in, const int* in_sizes, int n_in,
                              void* d_out, int out_size, void* d_ws, size_t ws_size,
                              hipStream_t stream)
{
  (void)in_sizes; (void)n_in; (void)out_size; (void)ws_size;
  const float* x    = (const float*)d_in[0];
  const int*   A    = (const int*)d_in[1];
  const float* mz   = (const float*)d_in[2];
  const float* e_at = (const float*)d_in[4];
  const float* Np   = (const float*)d_in[5];
  const float* w    = (const float*)d_in[6];
  const float* asrc = (const float*)d_in[7];
  const float* adst = (const float*)d_in[8];
  const float* bias = (const float*)d_in[9];
  float* out = (float*)d_out;

  char* ws = (char*)d_ws;
  unsigned short* wfrag = (unsigned short*)ws;                     // 256 KB
  unsigned short* hT    = (unsigned short*)(ws + 262144);          // 8 MB
  float* Rt    = (float*)(ws + 8650752);                           // 256 KB
  float* expd  = (float*)(ws + 8912896);                           // 256 KB
  float* expd2 = (float*)(ws + 9175040);                           // 256 KB
  unsigned long long* Abits = (unsigned long long*)(ws + 9437184); // 1 MB

  stage0<<<dim3(64), dim3(256), 0, stream>>>(w, wfrag);
  stageA<<<dim3(512), dim3(512), 0, stream>>>(x, e_at, Np, wfrag, asrc, adst,
                                              A, Abits, hT, Rt, expd, expd2);
  attnBC<<<dim3(512), dim3(512), 0, stream>>>((const unsigned*)Abits, hT,
                                              Rt, expd, expd2, bias, mz, out);
}

// Round 12
// 141.344 us; speedup vs baseline: 1.0681x; 1.0681x over previous
//
#include <hip/hip_runtime.h>

typedef __attribute__((ext_vector_type(8))) short          bf16x8;
typedef __attribute__((ext_vector_type(8))) unsigned short u16x8;
typedef __attribute__((ext_vector_type(4))) unsigned short u16x4;
typedef __attribute__((ext_vector_type(4))) float          f32x4;
typedef __attribute__((ext_vector_type(4))) unsigned int   u32x4;

union U8 { u16x8 u; bf16x8 b; u32x4 w; };
union U4 { u16x4 u; unsigned w[2]; };

__device__ __forceinline__ unsigned short f2bf(float f){
  unsigned u = __float_as_uint(f);
  return (unsigned short)((u + 0x7fffu + ((u >> 16) & 1u)) >> 16);
}
// pack two floats to bf16x2 (round-half-up): lo->low16, hi->high16. exact 0 preserved.
__device__ __forceinline__ unsigned pack_bf16(float lo, float hi){
  unsigned a = __float_as_uint(hi) + 0x8000u;
  unsigned b = __float_as_uint(lo) + 0x8000u;
  return __builtin_amdgcn_perm(a, b, 0x07060302u);
}
// max-pair -> packed bf16 (RNE) -> halfword mask (0xFFFF/0x0000 halves).
__device__ __forceinline__ unsigned maskpack(float e0, float e1, unsigned m){
  unsigned r;
  asm("v_cvt_pk_bf16_f32 %0, %1, %2" : "=v"(r) : "v"(e0), "v"(e1));
  return r & m;
}

#define NN  1024
#define FIN 256
#define NH  8
#define FO  64

// ---------------------------------------------------------------------------
// Stage 0: wfrag = w in MFMA-B-frag layout only. grid 64 x 256.
// ---------------------------------------------------------------------------
__global__ __launch_bounds__(256) void stage0(
    const float* __restrict__ w, unsigned short* __restrict__ wfrag)
{
  const int tid = blockIdx.x * 256 + threadIdx.x;
  const int lane = tid & 63, ss = (tid >> 6) & 3, kc = (tid >> 8) & 7, h = tid >> 11;
  const int o = 16 * ss + (lane & 15);
  const int f = kc * 32 + (lane >> 4) * 8;
  u16x8 r;
  #pragma unroll
  for (int j = 0; j < 8; j++) r[j] = f2bf(w[(h * FIN + f + j) * FO + o]);
  *(u16x8*)(wfrag + tid * 8) = r;
}

// ---------------------------------------------------------------------------
// Stage A: flat grid 512, b = fid&7 (b-affine, R10's isolated -6us win:
// batch b's hT panel, exp tables and Abits all land in XCD b's L2 -- the
// same L2 attnB (b = fid&7) reads). 512-thr blocks, 8 waves = 8 heads.
// ---------------------------------------------------------------------------
__global__ __launch_bounds__(512, 4) void stageA(
    const float* __restrict__ x, const float* __restrict__ e_at,
    const float* __restrict__ Np, const unsigned short* __restrict__ wfrag,
    const float* __restrict__ a_src, const float* __restrict__ a_dst,
    const int* __restrict__ A, unsigned long long* __restrict__ Abits,
    unsigned short* __restrict__ hT,
    float* __restrict__ Rt, float* __restrict__ expd, float* __restrict__ expd2)
{
  __shared__ unsigned short rex[16 * 264];   // 16 rows x 256 f, pad 264
  const int t = threadIdx.x;
  const int fid = blockIdx.x;                // 512 blocks
  const int b = fid & 7, tile = fid >> 3;    // tile in [0,64)
  const int n0 = tile * 16;

  {                                          // cooperative recx tile build
    const int row = t >> 5, f0 = (t & 31) * 8;
    const int nrow = n0 + row;
    const float* ep = e_at + (b * NN + nrow) * FIN + f0;
    const float* qp = Np + nrow * FIN + f0;
    const float* xp = x + b * FIN + f0;
    f32x4 e0 = *(const f32x4*)ep, e1 = *(const f32x4*)(ep + 4);
    f32x4 q0 = *(const f32x4*)qp, q1 = *(const f32x4*)(qp + 4);
    f32x4 x0 = *(const f32x4*)xp, x1 = *(const f32x4*)(xp + 4);
    u16x8 r;
    #pragma unroll
    for (int j = 0; j < 4; j++){
      r[j]     = f2bf(e0[j] * q0[j] * x0[j]);
      r[j + 4] = f2bf(e1[j] * q1[j] * x1[j]);
    }
    *(u16x8*)(rex + row * 264 + f0) = r;
  }
  __syncthreads();

  const int h = t >> 6, lane = t & 63, quad = lane >> 4, l15 = lane & 15;
  const unsigned short* wf = wfrag + h * 16384 + lane * 8;

  f32x4 acc[4] = {};
  #pragma unroll
  for (int kc = 0; kc < 8; kc++){
    U8 a0, bf[4];
    a0.u = *(const u16x8*)(rex + l15 * 264 + kc * 32 + quad * 8);
    #pragma unroll
    for (int ss = 0; ss < 4; ss++) bf[ss].u = *(const u16x8*)(wf + (kc * 4 + ss) * 512);
    #pragma unroll
    for (int ss = 0; ss < 4; ss++)
      acc[ss] = __builtin_amdgcn_mfma_f32_16x16x32_bf16(a0.b, bf[ss].b, acc[ss], 0, 0, 0);
  }

  // panel store: [b,h,mtile,o(64),m(32)], C/D row(n)=quad*4+i, col(o)=16ss+l15
  {
    const int mtile = tile >> 1, moff = (tile & 1) * 16;
    unsigned short* pan = hT + (size_t)(((b * NH + h) * 32 + mtile) * 64) * 32;
    #pragma unroll
    for (int ss = 0; ss < 4; ss++){
      U4 v;
      v.w[0] = pack_bf16(acc[ss][0], acc[ss][1]);
      v.w[1] = pack_bf16(acc[ss][2], acc[ss][3]);
      *(u16x4*)(pan + (16 * ss + l15) * 32 + moff + quad * 4) = v.u;
    }
  }

  // s/d reductions -> exp tables (R = exp(0.8 s): row factor exp(0.2 s) cancels
  // in softmax, so P' = max(R*Ed, Ed2) gives identical attention weights)
  float as4[4], ad4[4];
  #pragma unroll
  for (int ss = 0; ss < 4; ss++){
    as4[ss] = a_src[h * FO + 16 * ss + l15];
    ad4[ss] = a_dst[h * FO + 16 * ss + l15];
  }
  #pragma unroll
  for (int i = 0; i < 4; i++){
    float ps = 0.f, pd = 0.f;
    #pragma unroll
    for (int ss = 0; ss < 4; ss++){ ps += acc[ss][i] * as4[ss]; pd += acc[ss][i] * ad4[ss]; }
    #pragma unroll
    for (int off = 1; off < 16; off <<= 1){
      ps += __shfl_xor(ps, off);
      pd += __shfl_xor(pd, off);
    }
    if (l15 == 0){
      const int idx = (b * NH + h) * NN + n0 + quad * 4 + i;
      Rt[idx]    = __expf(0.8f * ps);
      expd[idx]  = __expf(pd);
      expd2[idx] = __expf(0.2f * pd);
    }
  }

  // tail: adjacency bit-pack, b-affine (batch b's rows packed on XCD b)
  {
    const int seg = b * 1048576 + tile * 16384;      // int base
    #pragma unroll 4
    for (int k = 0; k < 32; k++){
      const int i = seg + k * 512 + t;
      unsigned long long m = __ballot(A[i] > 0);
      if ((t & 63) == 0) Abits[i >> 6] = m;
    }
  }
}

// ---------------------------------------------------------------------------
// Stage B: fused masked-softmax aggregation (best measured config, 145.0us
// total as R10). ZERO atomics, software-pipelined cur/next rotation.
// 1024 flat blocks of 256 thr; block = 1 head x 64 rows; 4 waves =
// 2 row-halves(rw) x 2 m-halves(mh); 32 rows x 512 cols per wave.
// This geometry is the measured pareto point: R9 (64-row waves) spills,
// R11 (16-row single-rg fused) doubles pan traffic + halves ILP; both lose.
// __launch_bounds__(256,4): 128 reg/wave budget (R3/R9 spill lesson).
// XCD decode b=fid&7; with b-affine stageA, pan reads are local-L2.
// (R6 lesson: never per-block __threadfence. R8 lesson: setprio/VALU-mask
// micro-opts are null-to-negative here.)
// ---------------------------------------------------------------------------
__global__ __launch_bounds__(256, 4) void attnB(
    const unsigned* __restrict__ Aw,
    const unsigned short* __restrict__ hT,
    const float* __restrict__ Rt,
    const float* __restrict__ expd, const float* __restrict__ expd2,
    float* __restrict__ hpart)
{
  // phase 1: smem[0..1023]=Ed, [1024..2047]=Ed2 (this head)
  // phase 2: smem[0..4159]=merge[64][65], smem[4160..4287]=den[2mh][64]
  __shared__ float smem[4288];
  __shared__ __align__(8) unsigned lut[16][2];   // nibble -> 2 halfword masks

  const int fid = blockIdx.x;
  const int b = fid & 7, h = (fid >> 3) & 7, rt = fid >> 6;  // rt in [0,16)
  const int n0 = rt * 64;

  const int t = threadIdx.x;                     // 256
  const int w = t >> 6, lane = t & 63, quad = lane >> 4, l15 = lane & 15;
  const int rw = w & 1, mh = w >> 1;
  const int nb = n0 + rw * 32;                   // wave's 32-row base

  if (t < 16){
    lut[t][0] = (t & 1 ? 0xFFFFu : 0u) | (t & 2 ? 0xFFFF0000u : 0u);
    lut[t][1] = (t & 4 ? 0xFFFFu : 0u) | (t & 8 ? 0xFFFF0000u : 0u);
  }
  {                                      // exp-table preload (1 head, coalesced)
    const float* s1 = expd  + (b * NH + h) * NN;
    const float* s2 = expd2 + (b * NH + h) * NN;
    *(f32x4*)(smem + t * 4)        = *(const f32x4*)(s1 + t * 4);
    *(f32x4*)(smem + 1024 + t * 4) = *(const f32x4*)(s2 + t * 4);
  }
  __syncthreads();

  const int hb = (b * NH + h) * NN;
  const float Rv0 = Rt[hb + nb + l15];
  const float Rv1 = Rt[hb + nb + 16 + l15];
  const unsigned short* pb = hT + (size_t)(b * NH + h) * 65536 + l15 * 32 + quad * 8;
  const float* edh = smem + quad * 8;
  const float* e2h = smem + 1024 + quad * 8;
  const unsigned* awp = Aw + (b * NN + nb) * 32;
  const int c0 = mh * 16;
  const int qs = quad * 8;

  // pipeline prologue: iter 0's pan frags + mask words
  U8 panc[4], pann[4];
  #pragma unroll
  for (int ss = 0; ss < 4; ss++)
    panc[ss].u = *(const u16x8*)(pb + (size_t)c0 * 2048 + ss * 512);
  unsigned mwc0 = awp[l15 * 32 + c0];
  unsigned mwc1 = awp[(16 + l15) * 32 + c0];
  unsigned mwn0, mwn1;

  U8 ones;                               // bf16 1.0 B-frag for row sums
  #pragma unroll
  for (int j = 0; j < 8; j++) ones.u[j] = 0x3F80;

  f32x4 acc0[4] = {}, acc1[4] = {};
  f32x4 accl0 = {}, accl1 = {};

  #pragma unroll
  for (int cc = 0; cc < 16; cc++){
    const int c = c0 + cc;
    // --- prefetch iter N+1 FIRST (L2 latency overlaps this whole iter) ---
    if (cc + 1 < 16){
      #pragma unroll
      for (int ss = 0; ss < 4; ss++)
        pann[ss].u = *(const u16x8*)(pb + (size_t)(c + 1) * 2048 + ss * 512);
      mwn0 = awp[l15 * 32 + c + 1];
      mwn1 = awp[(16 + l15) * 32 + c + 1];
    }
    // expand bit masks via LUT (mask words from previous iter's prefetch)
    const unsigned am0 = (mwc0 >> qs) & 0xFF;
    const unsigned am1 = (mwc1 >> qs) & 0xFF;
    const uint2 la0 = *(const uint2*)&lut[am0 & 15][0];
    const uint2 lb0 = *(const uint2*)&lut[(am0 >> 4) & 15][0];
    const uint2 la1 = *(const uint2*)&lut[am1 & 15][0];
    const uint2 lb1 = *(const uint2*)&lut[(am1 >> 4) & 15][0];
    // shared column factors (broadcast LDS reads, conflict-free)
    const f32x4 d01 = *(const f32x4*)(edh + c * 32);
    const f32x4 d23 = *(const f32x4*)(edh + c * 32 + 4);
    const f32x4 g01 = *(const f32x4*)(e2h + c * 32);
    const f32x4 g23 = *(const f32x4*)(e2h + c * 32 + 4);
    // P for row-group 0
    {
      const f32x4 p01 = Rv0 * d01, p23 = Rv0 * d23;
      U8 p;
      p.w[0] = maskpack(fmaxf(p01[0], g01[0]), fmaxf(p01[1], g01[1]), la0.x);
      p.w[1] = maskpack(fmaxf(p01[2], g01[2]), fmaxf(p01[3], g01[3]), la0.y);
      p.w[2] = maskpack(fmaxf(p23[0], g23[0]), fmaxf(p23[1], g23[1]), lb0.x);
      p.w[3] = maskpack(fmaxf(p23[2], g23[2]), fmaxf(p23[3], g23[3]), lb0.y);
      #pragma unroll
      for (int ss = 0; ss < 4; ss++)
        acc0[ss] = __builtin_amdgcn_mfma_f32_16x16x32_bf16(p.b, panc[ss].b, acc0[ss], 0, 0, 0);
      accl0 = __builtin_amdgcn_mfma_f32_16x16x32_bf16(p.b, ones.b, accl0, 0, 0, 0);
    }
    // P for row-group 1 (same pan frags -> panel traffic halved)
    {
      const f32x4 p01 = Rv1 * d01, p23 = Rv1 * d23;
      U8 p;
      p.w[0] = maskpack(fmaxf(p01[0], g01[0]), fmaxf(p01[1], g01[1]), la1.x);
      p.w[1] = maskpack(fmaxf(p01[2], g01[2]), fmaxf(p01[3], g01[3]), la1.y);
      p.w[2] = maskpack(fmaxf(p23[0], g23[0]), fmaxf(p23[1], g23[1]), lb1.x);
      p.w[3] = maskpack(fmaxf(p23[2], g23[2]), fmaxf(p23[3], g23[3]), lb1.y);
      #pragma unroll
      for (int ss = 0; ss < 4; ss++)
        acc1[ss] = __builtin_amdgcn_mfma_f32_16x16x32_bf16(p.b, panc[ss].b, acc1[ss], 0, 0, 0);
      accl1 = __builtin_amdgcn_mfma_f32_16x16x32_bf16(p.b, ones.b, accl1, 0, 0, 0);
    }
    // rotate (vanishes under full unroll via renaming)
    if (cc + 1 < 16){
      #pragma unroll
      for (int ss = 0; ss < 4; ss++) panc[ss] = pann[ss];
      mwc0 = mwn0; mwc1 = mwn1;
    }
  }

  __syncthreads();                       // tables dead; smem becomes merge buffer

  // denominators: accl[i] = complete row sum over this wave's m-half,
  // replicated over l15. Distinct (mh,rw,row) slots -> no atomics.
  float* den = smem + 4160;
  if (l15 == 0){
    #pragma unroll
    for (int i = 0; i < 4; i++){
      den[mh * 64 + rw * 32 + quad * 4 + i]      = accl0[i];
      den[mh * 64 + rw * 32 + 16 + quad * 4 + i] = accl1[i];
    }
  }
  // mh=1 waves park their numerators in merge[64][65]
  if (mh == 1){
    #pragma unroll
    for (int i = 0; i < 4; i++){
      const int r0 = rw * 32 + quad * 4 + i;
      #pragma unroll
      for (int ss = 0; ss < 4; ss++){
        smem[r0 * 65 + ss * 16 + l15]        = acc0[ss][i];
        smem[(r0 + 16) * 65 + ss * 16 + l15] = acc1[ss][i];
      }
    }
  }
  __syncthreads();

  // mh=0 waves: add halves, normalize, plain coalesced store to hpart
  if (mh == 0){
    float* hp = hpart + ((size_t)(b * NH + h) * NN + nb) * FO;
    #pragma unroll
    for (int i = 0; i < 4; i++){
      const int r = quad * 4 + i;
      const float ia = 1.0f / (den[rw * 32 + r] + den[64 + rw * 32 + r]);
      const float ib = 1.0f / (den[rw * 32 + 16 + r] + den[64 + rw * 32 + 16 + r]);
      #pragma unroll
      for (int ss = 0; ss < 4; ss++){
        hp[(size_t)r * FO + ss * 16 + l15] =
            (acc0[ss][i] + smem[(rw * 32 + r) * 65 + ss * 16 + l15]) * ia;
        hp[(size_t)(16 + r) * FO + ss * 16 + l15] =
            (acc1[ss][i] + smem[(rw * 32 + 16 + r) * 65 + ss * 16 + l15]) * ib;
      }
    }
  }
}

// ---------------------------------------------------------------------------
// Stage C: head mean + bias + mask. out = (0.125*sum_h hpart + bias) * mz.
// 16.8 MB streamed reads, 2 MB writes. grid 512 x 256, 4 outputs/thread.
// ---------------------------------------------------------------------------
__global__ __launch_bounds__(256) void stageC(
    const float* __restrict__ hpart, const float* __restrict__ bias,
    const float* __restrict__ mz, float* __restrict__ out)
{
  const int tid = blockIdx.x * 256 + threadIdx.x;    // 131072 threads
  const int o4 = (tid & 15) * 4;
  const int n  = (tid >> 4) & 1023;
  const int b  = tid >> 14;
  const size_t nf = (size_t)n * FO + o4;
  f32x4 s = {};
  #pragma unroll
  for (int h = 0; h < NH; h++)
    s += *(const f32x4*)(hpart + (size_t)(b * NH + h) * NN * FO + nf);
  const f32x4 bv = *(const f32x4*)(bias + o4);
  const float m = mz[b * NN + n];
  f32x4 r;
  #pragma unroll
  for (int j = 0; j < 4; j++) r[j] = (0.125f * s[j] + bv[j]) * m;
  *(f32x4*)(out + (size_t)b * NN * FO + nf) = r;
}

extern "C" void kernel_launch(void* const* d_in, const int* in_sizes, int n_in,
                              void* d_out, int out_size, void* d_ws, size_t ws_size,
                              hipStream_t stream)
{
  (void)in_sizes; (void)n_in; (void)out_size; (void)ws_size;
  const float* x    = (const float*)d_in[0];
  const int*   A    = (const int*)d_in[1];
  const float* mz   = (const float*)d_in[2];
  const float* e_at = (const float*)d_in[4];
  const float* Np   = (const float*)d_in[5];
  const float* w    = (const float*)d_in[6];
  const float* asrc = (const float*)d_in[7];
  const float* adst = (const float*)d_in[8];
  const float* bias = (const float*)d_in[9];
  float* out = (float*)d_out;

  char* ws = (char*)d_ws;
  unsigned short* wfrag = (unsigned short*)ws;                     // 256 KB
  unsigned short* hT    = (unsigned short*)(ws + 262144);          // 8 MB
  float* Rt    = (float*)(ws + 8650752);                           // 256 KB
  float* expd  = (float*)(ws + 8912896);                           // 256 KB
  float* expd2 = (float*)(ws + 9175040);                           // 256 KB
  unsigned long long* Abits = (unsigned long long*)(ws + 9437184); // 1 MB
  float* hpart = (float*)(ws + 10485760);                          // 16.8 MB

  stage0<<<dim3(64), dim3(256), 0, stream>>>(w, wfrag);
  stageA<<<dim3(512), dim3(512), 0, stream>>>(x, e_at, Np, wfrag, asrc, adst,
                                              A, Abits, hT, Rt, expd, expd2);
  attnB<<<dim3(1024), dim3(256), 0, stream>>>((const unsigned*)Abits, hT,
                                              Rt, expd, expd2, hpart);
  stageC<<<dim3(512), dim3(256), 0, stream>>>(hpart, bias, mz, out);
}